// Round 11
// baseline (88.597 us; speedup 1.0000x reference)
//
#include <hip/hip_runtime.h>
#include <cmath>
#include <cstdint>
#include <cstddef>

#define NT 8192     // tokens
#define MD 4096     // model dim
#define NE 64       // experts
#define NCHUNK 128  // NT/64

// Output layout (all float32):
// [0] l_loss | gates_k[2][NT] | idx[2][NT] | locations[2][NT]
static constexpr int OFF_GATES = 1;
static constexpr int OFF_IDX   = 1 + 2 * NT;
static constexpr int OFF_LOC   = 1 + 4 * NT;

typedef __attribute__((ext_vector_type(8)))  short short8_t;  // 8 bf16 (4 VGPR)
typedef __attribute__((ext_vector_type(16))) float f32x16;    // 32x32 MFMA C/D

// Exact 3-way truncation split: x == h + m + s + r, |r| <= 2^-24 |x|.
__device__ __forceinline__ void split3(float v, short& h, short& m, short& s) {
  unsigned bx = __float_as_uint(v);
  h = (short)(bx >> 16);
  float r1 = v - __uint_as_float(bx & 0xFFFF0000u);
  unsigned b1 = __float_as_uint(r1);
  m = (short)(b1 >> 16);
  float r2 = r1 - __uint_as_float(b1 & 0xFFFF0000u);
  s = (short)(__float_as_uint(r2) >> 16);
}

__device__ __forceinline__ void gload_lds16(const void* g, void* l) {
  __builtin_amdgcn_global_load_lds(
      (const __attribute__((address_space(1))) void*)g,
      (__attribute__((address_space(3))) void*)l, 16, 0, 0);
}

// K0: pack wg's bf16 3-split into 32x32x16 B-fragment order (r9/r10-verified):
// pkb[((g*2+n)*3+j)*64 + lane], g = K16-step (0..255), n = expert-32-group.
// Lane: col(expert) = n*32 + (lane&31), k = g*16 + 8*(lane>>5) + i.
// For a K32 step S the 12 slots [S*12, S*12+12) are CONTIGUOUS (12 KB) ->
// k1 stages them with a single linear global_load_lds sweep.
__global__ __launch_bounds__(64)
void k0_pack(const float* __restrict__ wg, short8_t* __restrict__ pkb) {
  const int lane = threadIdx.x;
  const int n    = blockIdx.x & 1;
  const int g    = blockIdx.x >> 1;          // K16 step 0..255
  const int e    = n * 32 + (lane & 31);
  const int k0   = g * 16 + (lane >> 5) * 8;
  const float* src = wg + (size_t)e * MD + k0;
  float4 v0 = *(const float4*)(src);
  float4 v1 = *(const float4*)(src + 4);
  float av[8] = {v0.x, v0.y, v0.z, v0.w, v1.x, v1.y, v1.z, v1.w};
  short8_t h, m, s;
#pragma unroll
  for (int i = 0; i < 8; ++i) {
    short a, b, c; split3(av[i], a, b, c);
    h[i] = a; m[i] = b; s[i] = c;
  }
  short8_t* base = pkb + ((size_t)(g * 2 + n) * 3) * 64 + lane;
  base[0]   = h;
  base[64]  = m;
  base[128] = s;
}

#define BM   64   // tokens per block
#define ROWP 40   // A-LDS row stride in shorts (32 data + 8 pad = 80 B)

// K1: logits-partial = x[64-token tile] . wg^T over a 512-wide k-chunk via
// 32x32x16 bf16 MFMA 3-split (6 term-pairs == fp32 accuracy).
// BOTH operands consumed from LDS (the r4 lesson: keep global latency off the
// MFMA critical path, decoupled by double buffering):
//   - A: ideally-coalesced global reads -> split3 in reg -> padded LDS.
//   - B: pure DMA global_load_lds from pkb (12 KB/step, linear dest,
//     3 instr/thread, zero VALU), read back lane*16 contiguous (conflict-free).
// One barrier per step. 4 waves = (token-half wh, expert-group nh).
// LDS 55 KB -> 2 blocks/CU (8 waves/CU). grid (128, 8).
template <int NS>   // K32 steps per chunk
__global__ __launch_bounds__(256, 2)
void k1_gemm(const float* __restrict__ x, const short8_t* __restrict__ pkb,
             float* __restrict__ part) {
  __shared__ short Ah[2][BM * ROWP], Am[2][BM * ROWP], As[2][BM * ROWP];
  __shared__ short Bl[2][768 * 8];   // 12 KB per buffer, fragment-linear
  const int tid   = threadIdx.x;
  const int lane  = tid & 63;
  const int w     = tid >> 6;
  const int wh    = w >> 1;            // token 32-half
  const int nh    = w & 1;             // expert 32-group
  const int mt    = blockIdx.x;
  const int chunk = blockIdx.y;
  const int kc    = chunk * NS * 32;

  // ---- A staging: thread -> rows r0=tid>>3, r0+32; float4 q=tid&7.
  // One wave-instr = 8 rows x 128B = 8 fully-consumed lines.
  const int r0 = tid >> 3;
  const int q  = tid & 7;
  const float* g0 = x + (size_t)(mt * BM + r0) * MD + kc + q * 4;
  const float* g1 = g0 + (size_t)32 * MD;
  const int so0 = r0 * ROWP + q * 4;
  const int so1 = (r0 + 32) * ROWP + q * 4;

  float4 c0, c1;
  auto cvt_write = [&](int buf) {
    float v0[4] = {c0.x, c0.y, c0.z, c0.w};
    float v1[4] = {c1.x, c1.y, c1.z, c1.w};
    short4 h4, m4, s4;
    split3(v0[0], h4.x, m4.x, s4.x); split3(v0[1], h4.y, m4.y, s4.y);
    split3(v0[2], h4.z, m4.z, s4.z); split3(v0[3], h4.w, m4.w, s4.w);
    *(short4*)&Ah[buf][so0] = h4;
    *(short4*)&Am[buf][so0] = m4;
    *(short4*)&As[buf][so0] = s4;
    split3(v1[0], h4.x, m4.x, s4.x); split3(v1[1], h4.y, m4.y, s4.y);
    split3(v1[2], h4.z, m4.z, s4.z); split3(v1[3], h4.w, m4.w, s4.w);
    *(short4*)&Ah[buf][so1] = h4;
    *(short4*)&Am[buf][so1] = m4;
    *(short4*)&As[buf][so1] = s4;
  };

  // ---- B staging: DMA 12 KB (768 x 16B slots) pkb -> LDS, linear.
  auto stage_B = [&](int buf, int s) {
    const short8_t* src = pkb + (size_t)(chunk * NS + s) * 768 + tid;
#pragma unroll
    for (int j = 0; j < 3; ++j)
      gload_lds16(src + j * 256, &Bl[buf][(tid + j * 256) * 8]);
  };

  const int arow = wh * 32 + (lane & 31);      // A-frag row (token)
  const int half = lane >> 5;                  // k-octet half

  f32x16 acc;
#pragma unroll
  for (int r = 0; r < 16; ++r) acc[r] = 0.f;

  auto compute = [&](int buf) {
#pragma unroll
    for (int t = 0; t < 2; ++t) {              // two K16 sub-steps, ascending k
      const int ao = arow * ROWP + t * 16 + half * 8;
      short8_t a_h = *(const short8_t*)&Ah[buf][ao];
      short8_t a_m = *(const short8_t*)&Am[buf][ao];
      short8_t a_s = *(const short8_t*)&As[buf][ao];
      const int bs = ((t * 2 + nh) * 3) * 64 + lane;   // short8 slot
      short8_t b_h = *(const short8_t*)&Bl[buf][(bs) * 8];
      short8_t b_m = *(const short8_t*)&Bl[buf][(bs + 64) * 8];
      short8_t b_s = *(const short8_t*)&Bl[buf][(bs + 128) * 8];
      acc = __builtin_amdgcn_mfma_f32_32x32x16_bf16(a_h, b_h, acc, 0, 0, 0);
      acc = __builtin_amdgcn_mfma_f32_32x32x16_bf16(a_h, b_m, acc, 0, 0, 0);
      acc = __builtin_amdgcn_mfma_f32_32x32x16_bf16(a_m, b_h, acc, 0, 0, 0);
      acc = __builtin_amdgcn_mfma_f32_32x32x16_bf16(a_h, b_s, acc, 0, 0, 0);
      acc = __builtin_amdgcn_mfma_f32_32x32x16_bf16(a_s, b_h, acc, 0, 0, 0);
      acc = __builtin_amdgcn_mfma_f32_32x32x16_bf16(a_m, b_m, acc, 0, 0, 0);
    }
  };

  // prologue
  stage_B(0, 0);
  c0 = *(const float4*)(g0);
  c1 = *(const float4*)(g1);
  cvt_write(0);
  __syncthreads();   // drains the B DMA (vmcnt) + A writes (lgkmcnt)

  int buf = 0;
  for (int s = 0; s < NS; ++s) {
    float4 t0, t1;
    if (s + 1 < NS) {
      stage_B(buf ^ 1, s + 1);                 // DMA next B (L2-hot)
      t0 = *(const float4*)(g0 + (s + 1) * 32);  // prefetch next A (HBM)
      t1 = *(const float4*)(g1 + (s + 1) * 32);
    }
    compute(buf);                              // LDS-only consumption
    if (s + 1 < NS) {
      c0 = t0; c1 = t1;
      cvt_write(buf ^ 1);
    }
    __syncthreads();                           // single barrier per step
    buf ^= 1;
  }

  // C/D layout (m74/m101 verified): col=lane&31, row=(r&3)+8*(r>>2)+4*(lane>>5)
  const int col = lane & 31;
#pragma unroll
  for (int r = 0; r < 16; ++r) {
    const int rw = (r & 3) + 8 * (r >> 2) + 4 * half;
    const int dt = mt * BM + wh * 32 + rw;
    part[((size_t)chunk * NT + dt) * NE + nh * 32 + col] = acc[r];
  }
}

// K2a: fold k-chunk partials into part[0], chunk-ascending (deterministic).
// 512 blocks x 256 thr, coalesced float4 streams.
__global__ __launch_bounds__(256)
void k2a_fold(float* __restrict__ part, int ks) {
  const size_t i = (size_t)blockIdx.x * blockDim.x + threadIdx.x;
  float4* p = (float4*)part;
  float4 v = p[i];
  for (int c = 1; c < ks; ++c) {
    float4 u = p[(size_t)c * (NT * NE / 4) + i];
    v.x += u.x; v.y += u.y; v.z += u.z; v.w += u.w;
  }
  p[i] = v;
}

// K2b: per-token top-2/softmax/gates/idx + per-chunk counts (transposed),
// in-chunk ranks (ballot/popcount), gate column sums (transposed).
// grid 128, block 64. Reads folded part[0] (2 MB, L2/L3-hot).
__global__ void k2b_topk(const float* __restrict__ part, float* __restrict__ out,
                         float* __restrict__ meT,
                         int* __restrict__ cntT0, int* __restrict__ cntT1,
                         int* __restrict__ rank0, int* __restrict__ rank1) {
  const int lane  = threadIdx.x;
  const int chunk = blockIdx.x;
  const int token = chunk * 64 + lane;

  float l[NE];
  const float4* p4 = (const float4*)(part + (size_t)token * NE);
#pragma unroll
  for (int qq = 0; qq < 16; ++qq) {
    float4 v = p4[qq];
    l[4*qq+0] = v.x; l[4*qq+1] = v.y; l[4*qq+2] = v.z; l[4*qq+3] = v.w;
  }

  // jax tie-break (lowest index wins): strict > ascending scans
  float m1 = -INFINITY; int i1 = 0;
#pragma unroll
  for (int e = 0; e < NE; ++e) if (l[e] > m1) { m1 = l[e]; i1 = e; }
  float m2 = -INFINITY; int i2 = 0;
#pragma unroll
  for (int e = 0; e < NE; ++e) if (e != i1 && l[e] > m2) { m2 = l[e]; i2 = e; }

  float s = 0.f;
#pragma unroll
  for (int e = 0; e < NE; ++e) { l[e] = __expf(l[e] - m1); s += l[e]; }
  const float inv_s = 1.f / s;

  const float g2 = __expf(m2 - m1);   // normalized top-2: softmax denom cancels
  const float dn = 1.f + g2;
  out[OFF_GATES + token]      = 1.f / dn;
  out[OFF_GATES + NT + token] = g2 / dn;
  out[OFF_IDX + token]        = (float)i1;
  out[OFF_IDX + NT + token]   = (float)i2;

  const unsigned long long below = (1ULL << lane) - 1ULL;
  for (int e = 0; e < NE; ++e) {
    unsigned long long ma = __ballot(i1 == e);
    unsigned long long mb = __ballot(i2 == e);
    if (i1 == e) rank0[token] = __popcll(ma & below);
    if (i2 == e) rank1[token] = __popcll(mb & below);
    if (lane == e) {
      cntT0[lane * NCHUNK + chunk] = __popcll(ma);
      cntT1[lane * NCHUNK + chunk] = __popcll(mb);
    }
  }

  // column sums of softmax gates over this chunk (transpose via padded LDS)
  __shared__ float lds[64 * 65];
#pragma unroll
  for (int e = 0; e < NE; ++e) lds[lane * 65 + e] = l[e] * inv_s;
  __syncthreads();
  float col = 0.f;
#pragma unroll
  for (int t = 0; t < 64; ++t) col += lds[t * 65 + lane];
  meT[lane * NCHUNK + chunk] = col;   // lane = expert
}

// K3b: exclusive scan of per-chunk counts (k0 then k1 so k1 bases start at
// ce[e]); lane-contiguous (transposed) layout. me reduce + l_loss. 1 wave.
__global__ void k3b_scan(const int* __restrict__ cntT0, const int* __restrict__ cntT1,
                         int* __restrict__ baseT0, int* __restrict__ baseT1,
                         const float* __restrict__ meT, float* __restrict__ out) {
  const int e = threadIdx.x;
  const int* c0 = cntT0 + e * NCHUNK;
  const int* c1 = cntT1 + e * NCHUNK;
  int* b0 = baseT0 + e * NCHUNK;
  int* b1 = baseT1 + e * NCHUNK;
  int run = 0;
#pragma unroll 4
  for (int c = 0; c < NCHUNK; ++c) { b0[c] = run; run += c0[c]; }
  const int ce = run;
#pragma unroll 4
  for (int c = 0; c < NCHUNK; ++c) { b1[c] = run; run += c1[c]; }
  float me = 0.f;
  const float* mp = meT + e * NCHUNK;
#pragma unroll 4
  for (int c = 0; c < NCHUNK; ++c) me += mp[c];
  float v = me * (float)ce;
#pragma unroll
  for (int off = 1; off < 64; off <<= 1) v += __shfl_xor(v, off, 64);
  if (e == 0) out[0] = v * ((float)NE / ((float)NT * (float)NT));
}

// K3c: locations = chunk base + in-chunk rank. grid 128, block 64.
__global__ void k3c_loc(float* __restrict__ out,
                        const int* __restrict__ baseT0, const int* __restrict__ baseT1,
                        const int* __restrict__ rank0, const int* __restrict__ rank1) {
  const int lane  = threadIdx.x;
  const int chunk = blockIdx.x;
  const int token = chunk * 64 + lane;
  const int i1 = (int)out[OFF_IDX + token];
  const int i2 = (int)out[OFF_IDX + NT + token];
  out[OFF_LOC + token]      = (float)(baseT0[i1 * NCHUNK + chunk] + rank0[token]);
  out[OFF_LOC + NT + token] = (float)(baseT1[i2 * NCHUNK + chunk] + rank1[token]);
}

extern "C" void kernel_launch(void* const* d_in, const int* in_sizes, int n_in,
                              void* d_out, int out_size, void* d_ws, size_t ws_size,
                              hipStream_t stream) {
  const float* x  = (const float*)d_in[0];
  const float* wg = (const float*)d_in[1];
  float* out = (float*)d_out;

  const size_t pkb_sl = (size_t)256 * 2 * 3 * 64;      // short8 slots (1.5 MB)
  const size_t fixed_bytes = pkb_sl * 16
                           + (5 * (size_t)NE * NCHUNK + 2 * NT) * 4;
  int ks = 8;   // grid (128, 8) = 1024 blocks
  while (ks > 4 &&
         fixed_bytes + (size_t)ks * NT * NE * sizeof(float) > ws_size)
    ks >>= 1;

  short8_t* pkb = (short8_t*)d_ws;
  float* part = (float*)((char*)d_ws + pkb_sl * 16);    // [ks][NT][NE]
  float* meT  = part + (size_t)ks * NT * NE;            // [64][128]
  int* cntT0  = (int*)(meT + NE * NCHUNK);
  int* cntT1  = cntT0 + NE * NCHUNK;
  int* baseT0 = cntT1 + NE * NCHUNK;
  int* baseT1 = baseT0 + NE * NCHUNK;
  int* rank0  = baseT1 + NE * NCHUNK;                   // [NT]
  int* rank1  = rank0 + NT;

  hipLaunchKernelGGL(k0_pack, dim3(512), dim3(64), 0, stream, wg, pkb);
  if (ks == 8)
    hipLaunchKernelGGL((k1_gemm<16>), dim3(NT / BM, 8), dim3(256), 0, stream,
                       x, pkb, part);
  else
    hipLaunchKernelGGL((k1_gemm<32>), dim3(NT / BM, 4), dim3(256), 0, stream,
                       x, pkb, part);
  hipLaunchKernelGGL(k2a_fold, dim3(NT * NE / 4 / 256), dim3(256), 0, stream,
                     part, ks);
  hipLaunchKernelGGL(k2b_topk, dim3(NCHUNK), dim3(64), 0, stream,
                     part, out, meT, cntT0, cntT1, rank0, rank1);
  hipLaunchKernelGGL(k3b_scan, dim3(1), dim3(64), 0, stream,
                     cntT0, cntT1, baseT0, baseT1, meT, out);
  hipLaunchKernelGGL(k3c_loc, dim3(NCHUNK), dim3(64), 0, stream,
                     out, baseT0, baseT1, rank0, rank1);
}

// Round 12
// 83.282 us; speedup vs baseline: 1.0638x; 1.0638x over previous
//
#include <hip/hip_runtime.h>
#include <cmath>
#include <cstdint>
#include <cstddef>

#define NT 8192     // tokens
#define MD 4096     // model dim
#define NE 64       // experts
#define NCHUNK 128  // NT/64

// Output layout (all float32):
// [0] l_loss | gates_k[2][NT] | idx[2][NT] | locations[2][NT]
static constexpr int OFF_GATES = 1;
static constexpr int OFF_IDX   = 1 + 2 * NT;
static constexpr int OFF_LOC   = 1 + 4 * NT;

typedef __attribute__((ext_vector_type(8)))  short short8_t;  // 8 bf16 (4 VGPR)
typedef __attribute__((ext_vector_type(16))) float f32x16;    // 32x32 MFMA C/D

// Exact 3-way truncation split: x == h + m + s + r, |r| <= 2^-24 |x|.
__device__ __forceinline__ void split3(float v, short& h, short& m, short& s) {
  unsigned bx = __float_as_uint(v);
  h = (short)(bx >> 16);
  float r1 = v - __uint_as_float(bx & 0xFFFF0000u);
  unsigned b1 = __float_as_uint(r1);
  m = (short)(b1 >> 16);
  float r2 = r1 - __uint_as_float(b1 & 0xFFFF0000u);
  s = (short)(__float_as_uint(r2) >> 16);
}

__device__ __forceinline__ void gload_lds16(const void* g, void* l) {
  __builtin_amdgcn_global_load_lds(
      (const __attribute__((address_space(1))) void*)g,
      (__attribute__((address_space(3))) void*)l, 16, 0, 0);
}

// K0: pack wg's bf16 3-split into 32x32x16 B-fragment order (r9-r11-verified):
// pkb[((g*2+n)*3+j)*64 + lane]; col(expert)=n*32+(lane&31), k=g*16+8*(lane>>5)+i.
// A K32 step's 12 slots are contiguous (12 KB) -> staged by linear DMA in k1.
__global__ __launch_bounds__(64)
void k0_pack(const float* __restrict__ wg, short8_t* __restrict__ pkb) {
  const int lane = threadIdx.x;
  const int n    = blockIdx.x & 1;
  const int g    = blockIdx.x >> 1;          // K16 step 0..255
  const int e    = n * 32 + (lane & 31);
  const int k0   = g * 16 + (lane >> 5) * 8;
  const float* src = wg + (size_t)e * MD + k0;
  float4 v0 = *(const float4*)(src);
  float4 v1 = *(const float4*)(src + 4);
  float av[8] = {v0.x, v0.y, v0.z, v0.w, v1.x, v1.y, v1.z, v1.w};
  short8_t h, m, s;
#pragma unroll
  for (int i = 0; i < 8; ++i) {
    short a, b, c; split3(av[i], a, b, c);
    h[i] = a; m[i] = b; s[i] = c;
  }
  short8_t* base = pkb + ((size_t)(g * 2 + n) * 3) * 64 + lane;
  base[0]   = h;
  base[64]  = m;
  base[128] = s;
}

#define BM 64   // tokens per block

// K1: counted-vmcnt DMA pipeline (T3+T4), both operands via global_load_lds.
//  - A: raw fp32 x tile [64][32] DMA'd with col-swizzle c^=row&7 applied on
//    the per-lane GLOBAL source (linear LDS dest - rule #21); split3 happens
//    after the LDS read, in-reg, feeding MFMA directly.
//  - B: pre-split pkb fragments DMA'd linearly (12 KB/step).
//  - 3 buffers; per step: STAGE(s+2) -> s_waitcnt vmcnt(10) -> s_barrier ->
//    compute(s) -> s_barrier. vmcnt never drains to 0 in steady state:
//    ~2 steps x 20 KB stay in flight per block (the MLP the r6-r11 variants
//    never had). Raw s_barrier (NOT __syncthreads) to avoid the vmcnt(0) drain.
// 4 waves = (token-half wh, expert-group nh). LDS 60 KB -> 2 blocks/CU.
template <int NS>   // K32 steps per chunk
__global__ __launch_bounds__(256, 2)
void k1_gemm(const float* __restrict__ x, const short8_t* __restrict__ pkb,
             float* __restrict__ part) {
  __shared__ float Xs[3][BM * 32];   // 8 KB each; slot(row,c) holds col c^(row&7)
  __shared__ short Bs[3][768 * 8];   // 12 KB each, fragment-linear
  const int tid   = threadIdx.x;
  const int lane  = tid & 63;
  const int w     = tid >> 6;
  const int wh    = w >> 1;            // token 32-half
  const int nh    = w & 1;             // expert 32-group
  const int mt    = blockIdx.x;
  const int chunk = blockIdx.y;
  const int kc    = chunk * NS * 32;

  // A staging slots: j*256+tid -> (row, c); source col = c ^ (row&7)
  const int ra0 = tid >> 3,          ca0 = tid & 7;
  const int ra1 = (tid + 256) >> 3,  ca1 = tid & 7;
  const float* ga0 = x + (size_t)(mt * BM + ra0) * MD + kc + (ca0 ^ (ra0 & 7)) * 4;
  const float* ga1 = x + (size_t)(mt * BM + ra1) * MD + kc + (ca1 ^ (ra1 & 7)) * 4;
  const short8_t* gb = pkb + (size_t)chunk * NS * 768 + tid;

  auto STAGE = [&](int b, int s) {
    gload_lds16(ga0 + s * 32, &Xs[b][tid * 4]);
    gload_lds16(ga1 + s * 32, &Xs[b][(tid + 256) * 4]);
    const short8_t* src = gb + (size_t)s * 768;
    gload_lds16(src,       &Bs[b][tid * 8]);
    gload_lds16(src + 256, &Bs[b][(tid + 256) * 8]);
    gload_lds16(src + 512, &Bs[b][(tid + 512) * 8]);
  };

  const int arow = wh * 32 + (lane & 31);   // A-frag row (token)
  const int half = lane >> 5;               // k-octet half
  const int asw  = arow & 7;

  f32x16 acc;
#pragma unroll
  for (int r = 0; r < 16; ++r) acc[r] = 0.f;

  auto COMPUTE = [&](int b) {
#pragma unroll
    for (int t = 0; t < 2; ++t) {           // two K16 sub-steps, ascending k
      const int d0 = t * 4 + half * 2;      // float4 col of 8-float fragment
      float4 xa = *(const float4*)&Xs[b][(arow * 8 + (d0 ^ asw)) * 4];
      float4 xb = *(const float4*)&Xs[b][(arow * 8 + ((d0 + 1) ^ asw)) * 4];
      float av[8] = {xa.x, xa.y, xa.z, xa.w, xb.x, xb.y, xb.z, xb.w};
      short8_t a_h, a_m, a_s;
#pragma unroll
      for (int i = 0; i < 8; ++i) {
        short h, m, q; split3(av[i], h, m, q);
        a_h[i] = h; a_m[i] = m; a_s[i] = q;
      }
      const int bs = ((t * 2 + nh) * 3) * 64 + lane;   // short8 slot
      short8_t b_h = *(const short8_t*)&Bs[b][bs * 8];
      short8_t b_m = *(const short8_t*)&Bs[b][(bs + 64) * 8];
      short8_t b_s = *(const short8_t*)&Bs[b][(bs + 128) * 8];
      acc = __builtin_amdgcn_mfma_f32_32x32x16_bf16(a_h, b_h, acc, 0, 0, 0);
      acc = __builtin_amdgcn_mfma_f32_32x32x16_bf16(a_h, b_m, acc, 0, 0, 0);
      acc = __builtin_amdgcn_mfma_f32_32x32x16_bf16(a_m, b_h, acc, 0, 0, 0);
      acc = __builtin_amdgcn_mfma_f32_32x32x16_bf16(a_h, b_s, acc, 0, 0, 0);
      acc = __builtin_amdgcn_mfma_f32_32x32x16_bf16(a_s, b_h, acc, 0, 0, 0);
      acc = __builtin_amdgcn_mfma_f32_32x32x16_bf16(a_m, b_m, acc, 0, 0, 0);
    }
  };

  STAGE(0, 0);
  STAGE(1, 1);
#pragma unroll
  for (int s = 0; s < NS; ++s) {
    if (s + 2 < NS) STAGE((s + 2) % 3, s + 2);
    // retire only step-s's 5 loads; keep up to 2 future steps in flight
    if (s + 2 < NS)      asm volatile("s_waitcnt vmcnt(10)" ::: "memory");
    else if (s + 1 < NS) asm volatile("s_waitcnt vmcnt(5)" ::: "memory");
    else                 asm volatile("s_waitcnt vmcnt(0)" ::: "memory");
    __builtin_amdgcn_s_barrier();
    __builtin_amdgcn_sched_barrier(0);
    COMPUTE(s % 3);
    __builtin_amdgcn_sched_barrier(0);
    __builtin_amdgcn_s_barrier();   // all reads of buf s done before its reuse
  }

  // C/D layout (m74/m101 verified): col=lane&31, row=(r&3)+8*(r>>2)+4*(lane>>5)
  const int col = lane & 31;
#pragma unroll
  for (int r = 0; r < 16; ++r) {
    const int rw = (r & 3) + 8 * (r >> 2) + 4 * half;
    const int dt = mt * BM + wh * 32 + rw;
    part[((size_t)chunk * NT + dt) * NE + nh * 32 + col] = acc[r];
  }
}

// K2a: fold k-chunk partials into part[0], chunk-ascending (deterministic).
__global__ __launch_bounds__(256)
void k2a_fold(float* __restrict__ part, int ks) {
  const size_t i = (size_t)blockIdx.x * blockDim.x + threadIdx.x;
  float4* p = (float4*)part;
  float4 v = p[i];
  for (int c = 1; c < ks; ++c) {
    float4 u = p[(size_t)c * (NT * NE / 4) + i];
    v.x += u.x; v.y += u.y; v.z += u.z; v.w += u.w;
  }
  p[i] = v;
}

// K2b: per-token top-2/softmax/gates/idx + per-chunk counts (transposed),
// in-chunk ranks (ballot/popcount), gate column sums (transposed).
__global__ void k2b_topk(const float* __restrict__ part, float* __restrict__ out,
                         float* __restrict__ meT,
                         int* __restrict__ cntT0, int* __restrict__ cntT1,
                         int* __restrict__ rank0, int* __restrict__ rank1) {
  const int lane  = threadIdx.x;
  const int chunk = blockIdx.x;
  const int token = chunk * 64 + lane;

  float l[NE];
  const float4* p4 = (const float4*)(part + (size_t)token * NE);
#pragma unroll
  for (int qq = 0; qq < 16; ++qq) {
    float4 v = p4[qq];
    l[4*qq+0] = v.x; l[4*qq+1] = v.y; l[4*qq+2] = v.z; l[4*qq+3] = v.w;
  }

  // jax tie-break (lowest index wins): strict > ascending scans
  float m1 = -INFINITY; int i1 = 0;
#pragma unroll
  for (int e = 0; e < NE; ++e) if (l[e] > m1) { m1 = l[e]; i1 = e; }
  float m2 = -INFINITY; int i2 = 0;
#pragma unroll
  for (int e = 0; e < NE; ++e) if (e != i1 && l[e] > m2) { m2 = l[e]; i2 = e; }

  float s = 0.f;
#pragma unroll
  for (int e = 0; e < NE; ++e) { l[e] = __expf(l[e] - m1); s += l[e]; }
  const float inv_s = 1.f / s;

  const float g2 = __expf(m2 - m1);   // normalized top-2: softmax denom cancels
  const float dn = 1.f + g2;
  out[OFF_GATES + token]      = 1.f / dn;
  out[OFF_GATES + NT + token] = g2 / dn;
  out[OFF_IDX + token]        = (float)i1;
  out[OFF_IDX + NT + token]   = (float)i2;

  const unsigned long long below = (1ULL << lane) - 1ULL;
  for (int e = 0; e < NE; ++e) {
    unsigned long long ma = __ballot(i1 == e);
    unsigned long long mb = __ballot(i2 == e);
    if (i1 == e) rank0[token] = __popcll(ma & below);
    if (i2 == e) rank1[token] = __popcll(mb & below);
    if (lane == e) {
      cntT0[lane * NCHUNK + chunk] = __popcll(ma);
      cntT1[lane * NCHUNK + chunk] = __popcll(mb);
    }
  }

  // column sums of softmax gates over this chunk (transpose via padded LDS)
  __shared__ float lds[64 * 65];
#pragma unroll
  for (int e = 0; e < NE; ++e) lds[lane * 65 + e] = l[e] * inv_s;
  __syncthreads();
  float col = 0.f;
#pragma unroll
  for (int t = 0; t < 64; ++t) col += lds[t * 65 + lane];
  meT[lane * NCHUNK + chunk] = col;   // lane = expert
}

// K3b: exclusive scan of per-chunk counts (k0 then k1 so k1 bases start at
// ce[e]); lane-contiguous (transposed) layout. me reduce + l_loss. 1 wave.
__global__ void k3b_scan(const int* __restrict__ cntT0, const int* __restrict__ cntT1,
                         int* __restrict__ baseT0, int* __restrict__ baseT1,
                         const float* __restrict__ meT, float* __restrict__ out) {
  const int e = threadIdx.x;
  const int* c0 = cntT0 + e * NCHUNK;
  const int* c1 = cntT1 + e * NCHUNK;
  int* b0 = baseT0 + e * NCHUNK;
  int* b1 = baseT1 + e * NCHUNK;
  int run = 0;
#pragma unroll 4
  for (int c = 0; c < NCHUNK; ++c) { b0[c] = run; run += c0[c]; }
  const int ce = run;
#pragma unroll 4
  for (int c = 0; c < NCHUNK; ++c) { b1[c] = run; run += c1[c]; }
  float me = 0.f;
  const float* mp = meT + e * NCHUNK;
#pragma unroll 4
  for (int c = 0; c < NCHUNK; ++c) me += mp[c];
  float v = me * (float)ce;
#pragma unroll
  for (int off = 1; off < 64; off <<= 1) v += __shfl_xor(v, off, 64);
  if (e == 0) out[0] = v * ((float)NE / ((float)NT * (float)NT));
}

// K3c: locations = chunk base + in-chunk rank. grid 128, block 64.
__global__ void k3c_loc(float* __restrict__ out,
                        const int* __restrict__ baseT0, const int* __restrict__ baseT1,
                        const int* __restrict__ rank0, const int* __restrict__ rank1) {
  const int lane  = threadIdx.x;
  const int chunk = blockIdx.x;
  const int token = chunk * 64 + lane;
  const int i1 = (int)out[OFF_IDX + token];
  const int i2 = (int)out[OFF_IDX + NT + token];
  out[OFF_LOC + token]      = (float)(baseT0[i1 * NCHUNK + chunk] + rank0[token]);
  out[OFF_LOC + NT + token] = (float)(baseT1[i2 * NCHUNK + chunk] + rank1[token]);
}

extern "C" void kernel_launch(void* const* d_in, const int* in_sizes, int n_in,
                              void* d_out, int out_size, void* d_ws, size_t ws_size,
                              hipStream_t stream) {
  const float* x  = (const float*)d_in[0];
  const float* wg = (const float*)d_in[1];
  float* out = (float*)d_out;

  const size_t pkb_sl = (size_t)256 * 2 * 3 * 64;      // short8 slots (1.5 MB)
  const size_t fixed_bytes = pkb_sl * 16
                           + (5 * (size_t)NE * NCHUNK + 2 * NT) * 4;
  int ks = 8;   // grid (128, 8) = 1024 blocks
  while (ks > 4 &&
         fixed_bytes + (size_t)ks * NT * NE * sizeof(float) > ws_size)
    ks >>= 1;

  short8_t* pkb = (short8_t*)d_ws;
  float* part = (float*)((char*)d_ws + pkb_sl * 16);    // [ks][NT][NE]
  float* meT  = part + (size_t)ks * NT * NE;            // [64][128]
  int* cntT0  = (int*)(meT + NE * NCHUNK);
  int* cntT1  = cntT0 + NE * NCHUNK;
  int* baseT0 = cntT1 + NE * NCHUNK;
  int* baseT1 = baseT0 + NE * NCHUNK;
  int* rank0  = baseT1 + NE * NCHUNK;                   // [NT]
  int* rank1  = rank0 + NT;

  hipLaunchKernelGGL(k0_pack, dim3(512), dim3(64), 0, stream, wg, pkb);
  if (ks == 8)
    hipLaunchKernelGGL((k1_gemm<16>), dim3(NT / BM, 8), dim3(256), 0, stream,
                       x, pkb, part);
  else
    hipLaunchKernelGGL((k1_gemm<32>), dim3(NT / BM, 4), dim3(256), 0, stream,
                       x, pkb, part);
  hipLaunchKernelGGL(k2a_fold, dim3(NT * NE / 4 / 256), dim3(256), 0, stream,
                     part, ks);
  hipLaunchKernelGGL(k2b_topk, dim3(NCHUNK), dim3(64), 0, stream,
                     part, out, meT, cntT0, cntT1, rank0, rank1);
  hipLaunchKernelGGL(k3b_scan, dim3(1), dim3(64), 0, stream,
                     cntT0, cntT1, baseT0, baseT1, meT, out);
  hipLaunchKernelGGL(k3c_loc, dim3(NCHUNK), dim3(64), 0, stream,
                     out, baseT0, baseT1, rank0, rank1);
}